// Round 11
// baseline (2081.046 us; speedup 1.0000x reference)
//
#include <hip/hip_runtime.h>
#include <math.h>

#define ICC   196
#define BLK   256
#define NCELL 195
#define WSTR  28     // dwords per cell in LDS: W1[12] b1[6] W2[6] b2[1] pad[3]

#define SFENCE __builtin_amdgcn_sched_barrier(0)

// One ReLU cell, weights from LDS (wave-uniform addr -> broadcast ds_read,
// all-VGPR operands, no SGPR-operand v_mov tax, no address VALU).
__device__ __forceinline__ float cellL(float xi, float y, const float* wl)
{
    float4 q0 = *reinterpret_cast<const float4*>(wl + 0);   // w1x0..3
    float4 q1 = *reinterpret_cast<const float4*>(wl + 4);   // w1x4,w1x5,w1y0,w1y1
    float4 q2 = *reinterpret_cast<const float4*>(wl + 8);   // w1y2..5
    float4 q3 = *reinterpret_cast<const float4*>(wl + 12);  // b1_0..3
    float4 q4 = *reinterpret_cast<const float4*>(wl + 16);  // b1_4,b1_5,w2_0,w2_1
    float4 q5 = *reinterpret_cast<const float4*>(wl + 20);  // w2_2..5
    float  e  = wl[24];                                     // b2
    float h0 = fmaxf(fmaf(y, q1.z, fmaf(xi, q0.x, q3.x)), 0.f);
    float h1 = fmaxf(fmaf(y, q1.w, fmaf(xi, q0.y, q3.y)), 0.f);
    float h2 = fmaxf(fmaf(y, q2.x, fmaf(xi, q0.z, q3.z)), 0.f);
    float h3 = fmaxf(fmaf(y, q2.y, fmaf(xi, q0.w, q3.w)), 0.f);
    float h4 = fmaxf(fmaf(y, q2.z, fmaf(xi, q1.x, q4.x)), 0.f);
    float h5 = fmaxf(fmaf(y, q2.w, fmaf(xi, q1.y, q4.y)), 0.f);
    float s0 = fmaf(h0, q4.z, fmaf(h1, q4.w, e));
    float s1 = fmaf(h2, q5.x, h3 * q5.y);
    float s2 = fmaf(h4, q5.z, h5 * q5.w);
    return fmaxf(s0 + (s1 + s2), 0.f);
}

// fence after每cell: bounds weight-load hoisting to <=1 cell (spill-proof)
#define CELL(XI, I) { y = cellL((XI), y, wlds + (I) * WSTR); SFENCE; }

#define BURST16(CB, X0, X1, X2, X3)      \
  {                                      \
    CELL(X0.x, (CB)+0)  CELL(X0.y, (CB)+1)  CELL(X0.z, (CB)+2)  CELL(X0.w, (CB)+3)  \
    CELL(X1.x, (CB)+4)  CELL(X1.y, (CB)+5)  CELL(X1.z, (CB)+6)  CELL(X1.w, (CB)+7)  \
    CELL(X2.x, (CB)+8)  CELL(X2.y, (CB)+9)  CELL(X2.z, (CB)+10) CELL(X2.w, (CB)+11) \
    CELL(X3.x, (CB)+12) CELL(X3.y, (CB)+13) CELL(X3.z, (CB)+14) CELL(X3.w, (CB)+15) \
  }

__global__ __launch_bounds__(BLK, 4) void rnn_kernel(
    const float* __restrict__ x,    // [P, 196]
    const float* __restrict__ W1,   // [195, 2, 6]
    const float* __restrict__ b1,   // [195, 6]
    const float* __restrict__ W2,   // [195, 6]
    const float* __restrict__ b2,   // [195]
    const float* __restrict__ Wf1,  // [2, 6]
    const float* __restrict__ bf1,  // [6]
    const float* __restrict__ Wf2,  // [6]
    const float* __restrict__ bf2,  // [1]
    float* __restrict__ out,        // [P]
    int npoints)
{
    __shared__ float wlds[NCELL * WSTR];   // 21840 B

    const int tid = threadIdx.x;
    const int p   = blockIdx.x * BLK + tid;
    const int pc  = (p < npoints) ? p : (npoints - 1);
    const float4* __restrict__ r4 =
        reinterpret_cast<const float4*>(x + (size_t)pc * ICC);

    // issue own x loads FIRST: their HBM latency overlaps the weight fill
    float4 A0,A1,A2,A3, B0,B1,B2,B3, T;
    A0 = r4[0]; A1 = r4[1]; A2 = r4[2]; A3 = r4[3];   // ch 0..15
    B0 = r4[4]; B1 = r4[5]; B2 = r4[6]; B3 = r4[7];   // ch 16..31
    T  = r4[48];                                      // ch 192..195
    SFENCE;

    // one-time weight fill (vector chunks, coalesced-ish, ~19.5 KB)
    for (int i = tid; i < NCELL * 3; i += BLK) {          // W1: 3 float4/cell
        int c = i / 3, pt = i - c * 3;
        float4 v = reinterpret_cast<const float4*>(W1)[i];
        *reinterpret_cast<float4*>(&wlds[c * WSTR + pt * 4]) = v;
    }
    for (int i = tid; i < NCELL * 3; i += BLK) {          // b1: 3 float2/cell
        int c = i / 3, pt = i - c * 3;
        float2 v = reinterpret_cast<const float2*>(b1)[i];
        *reinterpret_cast<float2*>(&wlds[c * WSTR + 12 + pt * 2]) = v;
    }
    for (int i = tid; i < NCELL * 3; i += BLK) {          // W2: 3 float2/cell
        int c = i / 3, pt = i - c * 3;
        float2 v = reinterpret_cast<const float2*>(W2)[i];
        *reinterpret_cast<float2*>(&wlds[c * WSTR + 18 + pt * 2]) = v;
    }
    for (int i = tid; i < NCELL; i += BLK) wlds[i * WSTR + 24] = b2[i];
    __syncthreads();   // weights visible (also waits own x loads; fine, needed soon)

    float y = A0.x;    // y0 = channel 0

    // 12 chunks of 16 cells; reload just-consumed buffer with chunk c+2.
    // No barriers in the loop: waves free-run, vmcnt/lgkmcnt per-wave counted.
    #pragma unroll 1
    for (int c2 = 0; c2 < 12; c2 += 2) {
        BURST16(c2 * 16, A0, A1, A2, A3);
        if (c2 < 10) {
            const float4* q = r4 + (c2 + 2) * 4;
            A0 = q[0]; A1 = q[1]; A2 = q[2]; A3 = q[3];
            SFENCE;
        }
        BURST16(c2 * 16 + 16, B0, B1, B2, B3);
        if (c2 < 10) {
            const float4* q = r4 + (c2 + 3) * 4;
            B0 = q[0]; B1 = q[1]; B2 = q[2]; B3 = q[3];
            SFENCE;
        }
    }

    // tail: cells 192..194 from LDS, then final sigmoid cell (weights via SMEM)
    CELL(T.x, 192)
    CELL(T.y, 193)
    CELL(T.z, 194)

    const float xf = T.w;
    float h0 = fmaxf(fmaf(y, Wf1[6],  fmaf(xf, Wf1[0], bf1[0])), 0.0f);
    float h1 = fmaxf(fmaf(y, Wf1[7],  fmaf(xf, Wf1[1], bf1[1])), 0.0f);
    float h2 = fmaxf(fmaf(y, Wf1[8],  fmaf(xf, Wf1[2], bf1[2])), 0.0f);
    float h3 = fmaxf(fmaf(y, Wf1[9],  fmaf(xf, Wf1[3], bf1[3])), 0.0f);
    float h4 = fmaxf(fmaf(y, Wf1[10], fmaf(xf, Wf1[4], bf1[4])), 0.0f);
    float h5 = fmaxf(fmaf(y, Wf1[11], fmaf(xf, Wf1[5], bf1[5])), 0.0f);
    float s0 = fmaf(h0, Wf2[0], fmaf(h1, Wf2[1], bf2[0]));
    float s1 = fmaf(h2, Wf2[2], h3 * Wf2[3]);
    float s2 = fmaf(h4, Wf2[4], h5 * Wf2[5]);
    float t  = s0 + (s1 + s2);

    if (p < npoints)
        out[p] = 1.0f / (1.0f + __expf(-t));
}

extern "C" void kernel_launch(void* const* d_in, const int* in_sizes, int n_in,
                              void* d_out, int out_size, void* d_ws, size_t ws_size,
                              hipStream_t stream) {
    const float* x   = (const float*)d_in[0];
    const float* W1  = (const float*)d_in[1];
    const float* b1  = (const float*)d_in[2];
    const float* W2  = (const float*)d_in[3];
    const float* b2  = (const float*)d_in[4];
    const float* Wf1 = (const float*)d_in[5];
    const float* bf1 = (const float*)d_in[6];
    const float* Wf2 = (const float*)d_in[7];
    const float* bf2 = (const float*)d_in[8];
    float* out = (float*)d_out;

    const int npoints = out_size;                 // B*N = 262144
    const int grid = (npoints + BLK - 1) / BLK;   // 1024 blocks -> 4/CU
    rnn_kernel<<<grid, BLK, 0, stream>>>(x, W1, b1, W2, b2,
                                         Wf1, bf1, Wf2, bf2, out, npoints);
}

// Round 12
// 107.331 us; speedup vs baseline: 19.3890x; 19.3890x over previous
//
#include <hip/hip_runtime.h>
#include <math.h>

#define ICC 196
#define BLK 256
#define PPB 512   // points per block: thread t owns p0+t and p0+t+256

typedef float f32x2 __attribute__((ext_vector_type(2)));
#define SFENCE __builtin_amdgcn_sched_barrier(0)

__device__ __forceinline__ f32x2 mk2(float a, float b) { f32x2 r; r.x = a; r.y = b; return r; }
__device__ __forceinline__ f32x2 sp2(float s)          { f32x2 r; r.x = s; r.y = s; return r; }
__device__ __forceinline__ f32x2 pfma(f32x2 a, f32x2 b, f32x2 c) {
    return __builtin_elementwise_fma(a, b, c);
}
__device__ __forceinline__ f32x2 pmax0(f32x2 a) {
    return __builtin_elementwise_max(a, sp2(0.0f));
}

// One ReLU cell for TWO independent points packed in f32x2 (R3-proven clean).
// Weights indexed with compile-time-constant i -> wave-uniform s_load;
// each splat/mov is amortized over both points.
__device__ __forceinline__ f32x2 cell2(f32x2 xi, f32x2 y, int i,
    const float* __restrict__ W1, const float* __restrict__ b1,
    const float* __restrict__ W2, const float* __restrict__ b2)
{
    const float* w1 = W1 + i * 12;
    const float* bb = b1 + i * 6;
    const float* w2 = W2 + i * 6;
    f32x2 h0 = pmax0(pfma(y, sp2(w1[6]),  pfma(xi, sp2(w1[0]), sp2(bb[0]))));
    f32x2 h1 = pmax0(pfma(y, sp2(w1[7]),  pfma(xi, sp2(w1[1]), sp2(bb[1]))));
    f32x2 h2 = pmax0(pfma(y, sp2(w1[8]),  pfma(xi, sp2(w1[2]), sp2(bb[2]))));
    f32x2 h3 = pmax0(pfma(y, sp2(w1[9]),  pfma(xi, sp2(w1[3]), sp2(bb[3]))));
    f32x2 h4 = pmax0(pfma(y, sp2(w1[10]), pfma(xi, sp2(w1[4]), sp2(bb[4]))));
    f32x2 h5 = pmax0(pfma(y, sp2(w1[11]), pfma(xi, sp2(w1[5]), sp2(bb[5]))));
    f32x2 s0 = pfma(h0, sp2(w2[0]), pfma(h1, sp2(w2[1]), sp2(b2[i])));
    f32x2 s1 = pfma(h2, sp2(w2[2]), h3 * sp2(w2[3]));
    f32x2 s2 = pfma(h4, sp2(w2[4]), h5 * sp2(w2[5]));
    return pmax0(s0 + (s1 + s2));
}

// 16 packed cells: channel k of point-A set (XA*) and point-B set (XB*).
#define B16(CB, XA0, XA1, XA2, XA3, XB0, XB1, XB2, XB3)                        \
  {                                                                            \
    y = cell2(mk2(XA0.x, XB0.x), y, (CB)+0,  W1, b1, W2, b2);                  \
    y = cell2(mk2(XA0.y, XB0.y), y, (CB)+1,  W1, b1, W2, b2);                  \
    y = cell2(mk2(XA0.z, XB0.z), y, (CB)+2,  W1, b1, W2, b2);                  \
    y = cell2(mk2(XA0.w, XB0.w), y, (CB)+3,  W1, b1, W2, b2);                  \
    y = cell2(mk2(XA1.x, XB1.x), y, (CB)+4,  W1, b1, W2, b2);                  \
    y = cell2(mk2(XA1.y, XB1.y), y, (CB)+5,  W1, b1, W2, b2);                  \
    y = cell2(mk2(XA1.z, XB1.z), y, (CB)+6,  W1, b1, W2, b2);                  \
    y = cell2(mk2(XA1.w, XB1.w), y, (CB)+7,  W1, b1, W2, b2);                  \
    y = cell2(mk2(XA2.x, XB2.x), y, (CB)+8,  W1, b1, W2, b2);                  \
    y = cell2(mk2(XA2.y, XB2.y), y, (CB)+9,  W1, b1, W2, b2);                  \
    y = cell2(mk2(XA2.z, XB2.z), y, (CB)+10, W1, b1, W2, b2);                  \
    y = cell2(mk2(XA2.w, XB2.w), y, (CB)+11, W1, b1, W2, b2);                  \
    y = cell2(mk2(XA3.x, XB3.x), y, (CB)+12, W1, b1, W2, b2);                  \
    y = cell2(mk2(XA3.y, XB3.y), y, (CB)+13, W1, b1, W2, b2);                  \
    y = cell2(mk2(XA3.z, XB3.z), y, (CB)+14, W1, b1, W2, b2);                  \
    y = cell2(mk2(XA3.w, XB3.w), y, (CB)+15, W1, b1, W2, b2);                  \
  }

__global__ __launch_bounds__(BLK, 2) void rnn_kernel(
    const float* __restrict__ x,    // [P, 196]
    const float* __restrict__ W1,   // [195, 2, 6]
    const float* __restrict__ b1,   // [195, 6]
    const float* __restrict__ W2,   // [195, 6]
    const float* __restrict__ b2,   // [195]
    const float* __restrict__ Wf1,  // [2, 6]
    const float* __restrict__ bf1,  // [6]
    const float* __restrict__ Wf2,  // [6]
    const float* __restrict__ bf2,  // [1]
    float* __restrict__ out,        // [P]
    int npoints)
{
    const int tid = threadIdx.x;
    const int p0  = blockIdx.x * PPB;
    const int pA  = p0 + tid;
    const int pB  = p0 + tid + BLK;
    const int pcA = (pA < npoints) ? pA : (npoints - 1);
    const int pcB = (pB < npoints) ? pB : (npoints - 1);
    // rows are 784 B = 16B-aligned -> dwordx4-legal
    const float4* __restrict__ rA4 =
        reinterpret_cast<const float4*>(x + (size_t)pcA * ICC);
    const float4* __restrict__ rB4 =
        reinterpret_cast<const float4*>(x + (size_t)pcB * ICC);

    // double-buffered 64B chunk sets per point (named regs, NO arrays) + tails
    float4 A0,A1,A2,A3, B0,B1,B2,B3;      // point A: cur/next
    float4 C0,C1,C2,C3, D0,D1,D2,D3;      // point B: cur/next
    float4 TA, TB;
    A0 = rA4[0]; A1 = rA4[1]; A2 = rA4[2]; A3 = rA4[3];
    C0 = rB4[0]; C1 = rB4[1]; C2 = rB4[2]; C3 = rB4[3];
    B0 = rA4[4]; B1 = rA4[5]; B2 = rA4[6]; B3 = rA4[7];
    D0 = rB4[4]; D1 = rB4[5]; D2 = rB4[6]; D3 = rB4[7];
    TA = rA4[48]; TB = rB4[48];
    SFENCE;                               // anchor issue point

    f32x2 y = mk2(A0.x, C0.x);            // y0 = channel 0 of each point

    // 12 chunks x 16 cells; reload just-consumed sets with chunk c+2.
    // No LDS, no barriers: waves free-run, compiler emits counted vmcnt;
    // a 16-cell packed burst (~1300 cyc) covers the in-flight reload.
    #pragma unroll 1
    for (int c2 = 0; c2 < 12; c2 += 2) {
        B16(c2 * 16, A0, A1, A2, A3, C0, C1, C2, C3);
        if (c2 < 10) {
            const float4* qa = rA4 + (c2 + 2) * 4;
            const float4* qb = rB4 + (c2 + 2) * 4;
            A0 = qa[0]; A1 = qa[1]; A2 = qa[2]; A3 = qa[3];
            C0 = qb[0]; C1 = qb[1]; C2 = qb[2]; C3 = qb[3];
            SFENCE;
        }
        B16(c2 * 16 + 16, B0, B1, B2, B3, D0, D1, D2, D3);
        if (c2 < 10) {
            const float4* qa = rA4 + (c2 + 3) * 4;
            const float4* qb = rB4 + (c2 + 3) * 4;
            B0 = qa[0]; B1 = qa[1]; B2 = qa[2]; B3 = qa[3];
            D0 = qb[0]; D1 = qb[1]; D2 = qb[2]; D3 = qb[3];
            SFENCE;
        }
    }

    // tail: cells 192..194 packed, then the final sigmoid cell per point
    y = cell2(mk2(TA.x, TB.x), y, 192, W1, b1, W2, b2);
    y = cell2(mk2(TA.y, TB.y), y, 193, W1, b1, W2, b2);
    y = cell2(mk2(TA.z, TB.z), y, 194, W1, b1, W2, b2);

    f32x2 xf = mk2(TA.w, TB.w);
    f32x2 h0 = pmax0(pfma(y, sp2(Wf1[6]),  pfma(xf, sp2(Wf1[0]), sp2(bf1[0]))));
    f32x2 h1 = pmax0(pfma(y, sp2(Wf1[7]),  pfma(xf, sp2(Wf1[1]), sp2(bf1[1]))));
    f32x2 h2 = pmax0(pfma(y, sp2(Wf1[8]),  pfma(xf, sp2(Wf1[2]), sp2(bf1[2]))));
    f32x2 h3 = pmax0(pfma(y, sp2(Wf1[9]),  pfma(xf, sp2(Wf1[3]), sp2(bf1[3]))));
    f32x2 h4 = pmax0(pfma(y, sp2(Wf1[10]), pfma(xf, sp2(Wf1[4]), sp2(bf1[4]))));
    f32x2 h5 = pmax0(pfma(y, sp2(Wf1[11]), pfma(xf, sp2(Wf1[5]), sp2(bf1[5]))));
    f32x2 s0 = pfma(h0, sp2(Wf2[0]), pfma(h1, sp2(Wf2[1]), sp2(bf2[0])));
    f32x2 s1 = pfma(h2, sp2(Wf2[2]), h3 * sp2(Wf2[3]));
    f32x2 s2 = pfma(h4, sp2(Wf2[4]), h5 * sp2(Wf2[5]));
    f32x2 t  = s0 + (s1 + s2);

    if (pA < npoints) out[pA] = 1.0f / (1.0f + __expf(-t.x));
    if (pB < npoints) out[pB] = 1.0f / (1.0f + __expf(-t.y));
}

extern "C" void kernel_launch(void* const* d_in, const int* in_sizes, int n_in,
                              void* d_out, int out_size, void* d_ws, size_t ws_size,
                              hipStream_t stream) {
    const float* x   = (const float*)d_in[0];
    const float* W1  = (const float*)d_in[1];
    const float* b1  = (const float*)d_in[2];
    const float* W2  = (const float*)d_in[3];
    const float* b2  = (const float*)d_in[4];
    const float* Wf1 = (const float*)d_in[5];
    const float* bf1 = (const float*)d_in[6];
    const float* Wf2 = (const float*)d_in[7];
    const float* bf2 = (const float*)d_in[8];
    float* out = (float*)d_out;

    const int npoints = out_size;                 // B*N = 262144
    const int grid = (npoints + PPB - 1) / PPB;   // 512 blocks -> 2/CU, 8 waves/CU
    rnn_kernel<<<grid, BLK, 0, stream>>>(x, W1, b1, W2, b2,
                                         Wf1, bf1, Wf2, bf2, out, npoints);
}